// Round 6
// baseline (166.759 us; speedup 1.0000x reference)
//
#include <hip/hip_runtime.h>
#include <math.h>

// LatentSDE (L=C=D=1, H=64). h/g/p/enc are scalar->scalar: tabulated exactly
// (build_tabs) over z in [-128,128] dz=1/16, x in [-8,8] dx=1/128.
// Scan: 8-lane groups (8 batch elems / wave), f(z,c) exact (8 units/lane,
// 3-stage DPP sum8). h/g interp from LDS (on-chain), p/e interp from global
// L1 (off-chain). |z| beyond table -> exact MLP fallback (LDS weights).
// Final reduction fused via last-block-done counter (reset by build_tabs).

#define B_SZ 8192
#define T_SZ 128
#define NZ   4096
#define NX   2048
#define ZSCALE 16.0f            // z in [-128,128], dz=1/16
#define ZOFF   2048.0f
#define XSCALE 128.0f           // x in [-8,8], dx=1/128
#define XOFF   1024.0f
#define HG_FLOATS (2*(NZ+1))                      // 8194
#define TAB_FLOATS (HG_FLOATS + (NZ+1) + (NX+1))  // 14340
#define NBLK (B_SZ/8)                             // 1024 scan blocks

#define LOG2E 1.4426950408889634f
#define LN2   0.6931471805599453f

#if __has_builtin(__builtin_amdgcn_exp2f)
#define EXP2F(x) __builtin_amdgcn_exp2f(x)
#else
#define EXP2F(x) __expf((x) * LN2)
#endif
#if __has_builtin(__builtin_amdgcn_logf)
#define LOG2F(x) __builtin_amdgcn_logf(x)
#else
#define LOG2F(x) (__logf(x) * LOG2E)
#endif
#if __has_builtin(__builtin_amdgcn_rcpf)
#define RCPF(x) __builtin_amdgcn_rcpf(x)
#else
#define RCPF(x) (1.0f / (x))
#endif
#if __has_builtin(__builtin_amdgcn_sqrtf)
#define SQRTF(x) __builtin_amdgcn_sqrtf(x)
#else
#define SQRTF(x) sqrtf(x)
#endif

template <int CTRL>
__device__ __forceinline__ float dpp_add(float v) {
  int t = __builtin_amdgcn_update_dpp(0, __float_as_int(v), CTRL, 0xF, 0xF, true);
  return v + __int_as_float(t);
}
// all-lanes sum within each 8-lane group (quad_perm xor1, xor2, half-mirror)
__device__ __forceinline__ float sum8(float v) {
  v = dpp_add<0xB1>(v);
  v = dpp_add<0x4E>(v);
  v = dpp_add<0x141>(v);
  return v;
}
// softplus in log2 space: input a*log2e, output softplus(a)*log2e
__device__ __forceinline__ float sp2(float a2) {
  return fmaxf(a2, 0.0f) + LOG2F(1.0f + EXP2F(-fabsf(a2)));
}
// precise softplus for table build
__device__ __forceinline__ float sp_precise(float a) {
  return fmaxf(a, 0.0f) + log1pf(expf(-fabsf(a)));
}

// ---------------- table build + counter reset ----------------
__global__ __launch_bounds__(256) void build_tabs(
    const float* __restrict__ hw1, const float* __restrict__ hb1,
    const float* __restrict__ hw2, const float* __restrict__ hb2,
    const float* __restrict__ gw1, const float* __restrict__ gb1,
    const float* __restrict__ gw2, const float* __restrict__ gb2,
    const float* __restrict__ pw1, const float* __restrict__ pb1,
    const float* __restrict__ pw2, const float* __restrict__ pb2,
    const float* __restrict__ ew1, const float* __restrict__ eb1,
    const float* __restrict__ ew2, const float* __restrict__ eb2,
    float* __restrict__ tabs, int* __restrict__ ctr)
{
  const int gid = blockIdx.x * 256 + threadIdx.x;
  if (gid == 0) *ctr = 0;
  float* hgt = tabs;                    // interleaved (h,g), 2*(NZ+1)
  float* pt  = tabs + HG_FLOATS;
  float* et  = pt + (NZ + 1);
  if (gid < 3 * (NZ + 1)) {
    const int net = gid / (NZ + 1);
    const int i   = gid - net * (NZ + 1);
    const float z = -128.0f + (float)i * (1.0f / ZSCALE);
    if (net == 0) {
      float s = 0.0f;
      for (int j = 0; j < 64; ++j)
        s = fmaf(sp_precise(fmaf(z, hw1[j], hb1[j])), hw2[j], s);
      hgt[2 * i] = s + hb2[0];
    } else if (net == 1) {
      float s = 0.0f;
      for (int j = 0; j < 64; ++j)
        s = fmaf(sp_precise(fmaf(z, gw1[j], gb1[j])), gw2[j], s);
      hgt[2 * i + 1] = 1.0f / (1.0f + expf(-(s + gb2[0])));
    } else {
      float s = 0.0f;
      for (int j = 0; j < 64; ++j)
        s = fmaf(sp_precise(fmaf(z, pw1[j], pb1[j])), pw2[j], s);
      pt[i] = s + pb2[0];
    }
  } else if (gid < TAB_FLOATS) {
    const int i = gid - 3 * (NZ + 1);
    const float x = -8.0f + (float)i * (1.0f / XSCALE);
    float s = 0.0f;
    for (int j = 0; j < 64; ++j)
      s = fmaf(sp_precise(fmaf(x, ew1[j], eb1[j])), ew2[j], s);
    et[i] = s + eb2[0];
  }
}

// ---------------- fused scan + reduction ----------------
__global__ __launch_bounds__(64) void sde_scan8(
    const float* __restrict__ xs, const float* __restrict__ ts,
    const float* __restrict__ noise_std, const float* __restrict__ eps0,
    const float* __restrict__ dW,
    const float* __restrict__ qw,  const float* __restrict__ qb,
    const float* __restrict__ fw1, const float* __restrict__ fb1,
    const float* __restrict__ fw2, const float* __restrict__ fb2,
    const float* __restrict__ hw1, const float* __restrict__ hb1,
    const float* __restrict__ hw2, const float* __restrict__ hb2,
    const float* __restrict__ gw1, const float* __restrict__ gb1,
    const float* __restrict__ gw2, const float* __restrict__ gb2,
    const float* __restrict__ pw1, const float* __restrict__ pb1,
    const float* __restrict__ pw2, const float* __restrict__ pb2,
    const float* __restrict__ pz0_mean, const float* __restrict__ pz0_logstd,
    const float* __restrict__ tabsrc,
    int* __restrict__ ctr, float* __restrict__ partA, float* __restrict__ partB,
    float* __restrict__ out)
{
  __shared__ __align__(16) float hgf[HG_FLOATS];
  __shared__ float wsm[576];      // prescaled h|g|p weights for exact fallback
  __shared__ float ra[8], rb[8];
  __shared__ float sA[64], sB[64];
  __shared__ int lastflag;

  const int tid = threadIdx.x;     // one wave per block
  const int li  = tid & 7;
  const int grp = tid >> 3;
  const int b   = blockIdx.x * 8 + grp;

  // stage hg table (float4) + fallback weights (prescaled)
  {
    const float4* s4 = (const float4*)tabsrc;
    float4* d4 = (float4*)hgf;
    for (int i = tid; i < HG_FLOATS / 4; i += 64) d4[i] = s4[i];
    if (tid < (HG_FLOATS & 3))
      hgf[(HG_FLOATS & ~3) + tid] = tabsrc[(HG_FLOATS & ~3) + tid];
  }
  wsm[0*64+tid]=hw1[tid]*LOG2E; wsm[1*64+tid]=hb1[tid]*LOG2E; wsm[2*64+tid]=hw2[tid]*LN2;
  wsm[3*64+tid]=gw1[tid]*LOG2E; wsm[4*64+tid]=gb1[tid]*LOG2E; wsm[5*64+tid]=gw2[tid]*LN2;
  wsm[6*64+tid]=pw1[tid]*LOG2E; wsm[7*64+tid]=pb1[tid]*LOG2E; wsm[8*64+tid]=pw2[tid]*LN2;
  __syncthreads();

  const float2* hgt = (const float2*)hgf;
  const float* ptab = tabsrc + HG_FLOATS;
  const float* etab = ptab + (NZ + 1);

  // f-net per-lane weights (units u*8+li), log2-prescaled
  float fwzs[8], fwcs[8], fb1s[8], fw2s[8];
  #pragma unroll
  for (int u = 0; u < 8; ++u) {
    const int j = u * 8 + li;
    fwzs[u]=fw1[j]*LOG2E; fwcs[u]=fw1[64+j]*LOG2E; fb1s[u]=fb1[j]*LOG2E; fw2s[u]=fw2[j]*LN2;
  }
  const float fb2s = fb2[0];
  const float hb2s = hb2[0], gb2s = gb2[0], pb2s = pb2[0];
  const float qw0=qw[0], qw1=qw[1], qb0=qb[0], qb1=qb[1];
  const float ns = noise_std[0];
  const float inv_ns = 1.0f / ns;
  const float nh_i2 = -0.5f * inv_ns * inv_ns;
  const float pm = pz0_mean[0], pls = pz0_logstd[0];

  auto eval3 = [&](float zz, float& hv, float& gv, float& pv) {
    const float zs = fmaf(zz, ZSCALE, ZOFF);
    if (zs >= 0.0f && zs <= (float)NZ) {     // in-table: interp
      int zi = (int)zs;                       // trunc == floor (zs>=0)
      zi = min(zi, NZ - 1);
      const float zf = zs - (float)zi;
      const float2 a = hgt[zi], b2 = hgt[zi + 1];
      hv = fmaf(zf, b2.x - a.x, a.x);
      gv = fmaf(zf, b2.y - a.y, a.y);
      const float p0 = ptab[zi], p1 = ptab[zi + 1];
      pv = fmaf(zf, p1 - p0, p0);
    } else {                                  // rare tail: exact MLPs
      float sh = 0.f, sg = 0.f, sp = 0.f;
      #pragma unroll
      for (int u2 = 0; u2 < 8; ++u2) {
        const int j = u2 * 8 + li;
        sh = fmaf(sp2(fmaf(zz, wsm[j],     wsm[64+j])),  wsm[128+j], sh);
        sg = fmaf(sp2(fmaf(zz, wsm[192+j], wsm[256+j])), wsm[320+j], sg);
        sp = fmaf(sp2(fmaf(zz, wsm[384+j], wsm[448+j])), wsm[512+j], sp);
      }
      hv = sum8(sh) + hb2s;
      const float gpre = sum8(sg) + gb2s;
      gv = RCPF(1.0f + EXP2F(-gpre * LOG2E));
      pv = sum8(sp) + pb2s;
    }
  };
  auto einterp = [&](float x) {
    const float s = fmaf(x, XSCALE, XOFF);
    int i = (int)floorf(s);
    i = min(max(i, 0), NX - 1);
    const float fr = s - (float)i;
    const float e0 = etab[i], e1 = etab[i + 1];
    return fmaf(fr, e1 - e0, e0);
  };

  // ---- prologue ----
  const float x0 = xs[b];
  float       x1 = xs[B_SZ + b];
  const float c0 = einterp(x0);
  float    c_cur = einterp(x1);
  const float qm  = fmaf(c0, qw0, qb0);
  const float qls = fmaf(c0, qw1, qb1);
  float z = fmaf(EXP2F(qls * LOG2E), eps0[b], qm);
  const float dqm = qm - pm;
  const float kl = (pls - qls)
                 + (EXP2F(2.0f * qls * LOG2E) + dqm * dqm)
                   * (0.5f * EXP2F(-2.0f * pls * LOG2E))
                 - 0.5f;

  float hv, gv, pv;
  eval3(z, hv, gv, pv);
  float lp_sum; { const float d = x0 - pv; lp_sum = nh_i2 * d * d; }
  float dw_cur = dW[b];
  float lr_sum = 0.0f;

  // ---- Euler-Maruyama scan ----
  for (int k = 0; k < T_SZ - 1; ++k) {
    const int   i2  = (k + 2 < T_SZ) ? (k + 2) : (T_SZ - 1);
    const float x2  = xs[i2 * B_SZ + b];
    const float dwn = (k + 1 < T_SZ - 1) ? dW[(k + 1) * B_SZ + b] : 0.0f;
    const float dt  = ts[k + 1] - ts[k];
    const float sq  = SQRTF(dt);

    float sf = 0.0f;
    #pragma unroll
    for (int u = 0; u < 8; ++u)
      sf = fmaf(sp2(fmaf(z, fwzs[u], fmaf(c_cur, fwcs[u], fb1s[u]))), fw2s[u], sf);
    const float fv = sum8(sf) + fb2s;

    const float uu = (fv - hv) * RCPF(gv);
    lr_sum = fmaf((0.5f * dt) * uu, uu, lr_sum);
    z = fmaf(gv * dw_cur, sq, fmaf(fv, dt, z));

    eval3(z, hv, gv, pv);                 // h,g for next step; p for lp now
    const float d = x1 - pv;
    lp_sum = fmaf(nh_i2 * d, d, lp_sum);

    x1 = x2; c_cur = einterp(x2); dw_cur = dwn;
  }

  // ---- block partials + last-block final reduce (deterministic order) ----
  if (li == 0) { ra[grp] = lp_sum; rb[grp] = kl + lr_sum; }
  __syncthreads();
  if (tid == 0) {
    float sa = 0.f, sb = 0.f;
    #pragma unroll
    for (int i = 0; i < 8; ++i) { sa += ra[i]; sb += rb[i]; }
    partA[blockIdx.x] = sa; partB[blockIdx.x] = sb;
    __threadfence();
    lastflag = (atomicAdd(ctr, 1) == NBLK - 1) ? 1 : 0;
  }
  __syncthreads();
  if (lastflag) {
    __threadfence();
    float sa = 0.f, sb = 0.f;
    for (int i = tid; i < NBLK; i += 64) { sa += partA[i]; sb += partB[i]; }
    sA[tid] = sa; sB[tid] = sb;
    __syncthreads();
    if (tid == 0) {
      float ta = 0.f, tb = 0.f;
      for (int i = 0; i < 64; ++i) { ta += sA[i]; tb += sB[i]; }
      out[0] = ta / (float)B_SZ
             + (float)T_SZ * (-__logf(ns) - 0.9189385332046727f);
      out[1] = tb / (float)B_SZ;
    }
  }
}

extern "C" void kernel_launch(void* const* d_in, const int* in_sizes, int n_in,
                              void* d_out, int out_size, void* d_ws, size_t ws_size,
                              hipStream_t stream) {
  const float* xs        = (const float*)d_in[0];
  const float* ts        = (const float*)d_in[1];
  const float* noise_std = (const float*)d_in[2];
  const float* eps0      = (const float*)d_in[3];
  const float* dW        = (const float*)d_in[4];
  const float* ew1 = (const float*)d_in[5];
  const float* eb1 = (const float*)d_in[6];
  const float* ew2 = (const float*)d_in[7];
  const float* eb2 = (const float*)d_in[8];
  const float* qw  = (const float*)d_in[9];
  const float* qb  = (const float*)d_in[10];
  const float* fw1 = (const float*)d_in[11];
  const float* fb1 = (const float*)d_in[12];
  const float* fw2 = (const float*)d_in[13];
  const float* fb2 = (const float*)d_in[14];
  const float* hw1 = (const float*)d_in[15];
  const float* hb1 = (const float*)d_in[16];
  const float* hw2 = (const float*)d_in[17];
  const float* hb2 = (const float*)d_in[18];
  const float* gw1 = (const float*)d_in[19];
  const float* gb1 = (const float*)d_in[20];
  const float* gw2 = (const float*)d_in[21];
  const float* gb2 = (const float*)d_in[22];
  const float* pw1 = (const float*)d_in[23];
  const float* pb1 = (const float*)d_in[24];
  const float* pw2 = (const float*)d_in[25];
  const float* pb2 = (const float*)d_in[26];
  const float* pz0_mean   = (const float*)d_in[27];
  const float* pz0_logstd = (const float*)d_in[28];
  float* out = (float*)d_out;

  float* tabs  = (float*)d_ws;                 // [TAB_FLOATS]
  int*   ctr   = (int*)(tabs + TAB_FLOATS);    // [1]
  float* partA = (float*)(ctr + 1);            // [NBLK]
  float* partB = partA + NBLK;                 // [NBLK]

  build_tabs<<<(TAB_FLOATS + 255) / 256, 256, 0, stream>>>(
      hw1, hb1, hw2, hb2, gw1, gb1, gw2, gb2,
      pw1, pb1, pw2, pb2, ew1, eb1, ew2, eb2, tabs, ctr);

  sde_scan8<<<NBLK, 64, 0, stream>>>(
      xs, ts, noise_std, eps0, dW, qw, qb,
      fw1, fb1, fw2, fb2, hw1, hb1, hw2, hb2,
      gw1, gb1, gw2, gb2, pw1, pb1, pw2, pb2,
      pz0_mean, pz0_logstd, tabs, ctr, partA, partB, out);
}